// Round 8
// baseline (334.165 us; speedup 1.0000x reference)
//
#include <hip/hip_runtime.h>
#include <hip/hip_fp16.h>
#include <math.h>

// ---------------------------------------------------------------------------
// GNN pool: 2x GCNConv(elu) + MLP(128) + Linear(15) + softmax
// N=100000, E=3200000, IN=3, HID=64, MLP_HID=128, K=15, fp32 in/out.
//
// Round-8 pipeline:
//   scatter (bucket by dst>>7) -> bscan -> csr_sort (LDS counting sort)
//   -> agg3 (wave/node, s1 FP16) -> agg64 (2 nodes/wave, half2 gathers,
//   writes a2 FP16) -> h1 (64-node tiles, 1563 blocks: a2h@W2 elu @Wm1 elu
//   -> mt FP16 [j][node]; tt LDS pad-68, conflict-free) -> h2 (mt@Wm2+softmax).
//
// r7 lesson: h1 at 782 blocks was latency-bound (occ 19%, VALU 41%) with
// 8-way stage-A write conflicts (fA stride 8 x row 128 = 0 mod 32). Smaller
// tiles double resident waves; pad-68 kills conflicts; fp16 a2 halves the
// stage-A stream and makes it L2-resident.
// ---------------------------------------------------------------------------

#define SPAN 128          // nodes per bucket
#define CAP  4608         // bucket capacity (mean 4092 + ~8 sigma)
#define CH   8192         // edges per scatter chunk
#define TTP  68           // tt row pad: (f*68+n) mod 32 varies with f -> <=2-way

__device__ __forceinline__ float elu(float v) { return v > 0.f ? v : expm1f(v); }

// ---- counting scatter: edges -> buckets by dst>>7, packed (dl<<17)|src ----
__global__ __launch_bounds__(256) void scatter_kernel(const int* __restrict__ src,
    const int* __restrict__ dst, int* __restrict__ cursor, unsigned* __restrict__ colb,
    int E, int NBK, int nChunks) {
    __shared__ int hist[1024];
    __shared__ unsigned gb[1024];
    int tid = threadIdx.x;
    for (int chunk = blockIdx.x; chunk < nChunks; chunk += gridDim.x) {
        for (int i = tid; i < NBK; i += 256) hist[i] = 0;
        __syncthreads();
        int base = chunk * CH;
        int cnt = min(CH, E - base);
        unsigned br[32], dt[32];
#pragma unroll
        for (int j = 0; j < 32; ++j) {
            int idx = j * 256 + tid;
            br[j] = 0xFFFFFFFFu;
            if (idx < cnt) {
                int e = base + idx;
                int s = src[e], d = dst[e];
                int b = d >> 7;
                int r = atomicAdd(&hist[b], 1);
                br[j] = ((unsigned)b << 13) | (unsigned)r;
                dt[j] = ((unsigned)(d & 127) << 17) | (unsigned)s;
            }
        }
        __syncthreads();
        for (int b = tid; b < NBK; b += 256) {
            int c = hist[b];
            gb[b] = (unsigned)(b * CAP) + (c ? (unsigned)atomicAdd(&cursor[b], c) : 0u);
        }
        __syncthreads();
#pragma unroll
        for (int j = 0; j < 32; ++j) {
            if (br[j] != 0xFFFFFFFFu) {
                int b = br[j] >> 13;
                int r = br[j] & 8191;
                unsigned pos = gb[b] + (unsigned)r;
                if (pos < (unsigned)(b + 1) * CAP) colb[pos] = dt[j];
            }
        }
        __syncthreads();
    }
}

// ---- exclusive scan over bucket counts -> bbase ----
__global__ __launch_bounds__(1024) void bscan_kernel(const int* __restrict__ cursor,
    int* __restrict__ bbase, int* __restrict__ row_ptr, int NBK, int N) {
    __shared__ int ls[1024];
    int t = threadIdx.x;
    int v = (t < NBK) ? min(cursor[t], CAP) : 0;
    ls[t] = v;
    __syncthreads();
    for (int off = 1; off < 1024; off <<= 1) {
        int xv = (t >= off) ? ls[t - off] : 0;
        __syncthreads();
        ls[t] += xv;
        __syncthreads();
    }
    if (t < NBK) bbase[t] = ls[t] - v;
    if (t == NBK - 1) row_ptr[N] = ls[t];
}

// ---- per-bucket counting sort: row_ptr, deg->dis, sx4, coalesced col ----
__global__ __launch_bounds__(256) void csr_sort_kernel(const unsigned* __restrict__ colb,
    const int* __restrict__ cursor, const int* __restrict__ bbase,
    const float* __restrict__ x, int* __restrict__ row_ptr, int* __restrict__ col,
    float* __restrict__ dis, float4* __restrict__ sx4, int N) {
    __shared__ unsigned ebuf[CAP];
    __shared__ int sbuf[CAP];
    __shared__ int cnt[SPAN], pref[SPAN], fill[SPAN];
    int b = blockIdx.x, tid = threadIdx.x;
    int n = min(cursor[b], CAP);
    int base = b * CAP, bb = bbase[b];
    if (tid < SPAN) cnt[tid] = 0;
    for (int i = tid; i < n; i += 256) ebuf[i] = colb[base + i];
    __syncthreads();
    for (int i = tid; i < n; i += 256) atomicAdd(&cnt[(ebuf[i] >> 17) & 127], 1);
    __syncthreads();
    if (tid < SPAN) pref[tid] = cnt[tid];
    __syncthreads();
    for (int off = 1; off < SPAN; off <<= 1) {
        int xv = (tid < SPAN && tid >= off) ? pref[tid - off] : 0;
        __syncthreads();
        if (tid < SPAN) pref[tid] += xv;
        __syncthreads();
    }
    if (tid < SPAN) {
        int ex = pref[tid] - cnt[tid];
        fill[tid] = ex;
        int node = b * SPAN + tid;
        if (node < N) {
            row_ptr[node] = bb + ex;
            float r = rsqrtf((float)(cnt[tid] + 1));
            dis[node] = r;
            float4 q;
            q.x = r * x[node * 3 + 0];
            q.y = r * x[node * 3 + 1];
            q.z = r * x[node * 3 + 2];
            q.w = 0.f;
            sx4[node] = q;
        }
    }
    __syncthreads();
    for (int i = tid; i < n; i += 256) {
        unsigned e = ebuf[i];
        int pos = atomicAdd(&fill[(e >> 17) & 127], 1);
        sbuf[pos] = (int)(e & 0x1FFFF);
    }
    __syncthreads();
    for (int i = tid; i < n; i += 256) col[bb + i] = sbuf[i];
}

// ---- layer 1: aggregate sx (float4) + W1 + bias + elu; s1h = fp16(dis*h1) ----
__global__ void agg3_kernel(const float4* __restrict__ sx4, const int* __restrict__ row_ptr,
                            const int* __restrict__ col, const float* __restrict__ dis,
                            const float* __restrict__ W1, const float* __restrict__ b1,
                            __half* __restrict__ s1h, int N) {
    int wave = (blockIdx.x * blockDim.x + threadIdx.x) >> 6;
    int lane = threadIdx.x & 63;
    if (wave >= N) return;
    int d = wave;
    int start = row_ptr[d], end = row_ptr[d + 1];
    float a0 = 0.f, a1 = 0.f, a2v = 0.f;
    for (int i = start + lane; i < end; i += 64) {
        float4 q = sx4[col[i]];
        a0 += q.x; a1 += q.y; a2v += q.z;
    }
#pragma unroll
    for (int off = 32; off; off >>= 1) {
        a0  += __shfl_xor(a0, off);
        a1  += __shfl_xor(a1, off);
        a2v += __shfl_xor(a2v, off);
    }
    float4 qd = sx4[d];   // self loop
    a0 += qd.x; a1 += qd.y; a2v += qd.z;
    float r = dis[d];
    float v = r * (a0 * W1[lane] + a1 * W1[64 + lane] + a2v * W1[128 + lane]) + b1[lane];
    s1h[(size_t)d * 64 + lane] = __float2half(r * elu(v));
}

// ---- layer 2: 2 nodes/wave, half2 gathers; writes a2h FP16 ----
__global__ void agg64_kernel(const __half2* __restrict__ s1h, const int* __restrict__ row_ptr,
                             const int* __restrict__ col, const float* __restrict__ dis,
                             __half2* __restrict__ a2h, int N) {
    int wave = (blockIdx.x * blockDim.x + threadIdx.x) >> 6;
    int lane = threadIdx.x & 63;
    int hl = lane & 31;
    int d = wave * 2 + (lane >> 5);
    bool act = d < N;
    int start = 0, end = 0;
    if (act) { start = row_ptr[d]; end = row_ptr[d + 1]; }
    float a0x = 0.f, a0y = 0.f, a1x = 0.f, a1y = 0.f;
    float a2x = 0.f, a2y = 0.f, a3x = 0.f, a3y = 0.f;
    float a4x = 0.f, a4y = 0.f, a5x = 0.f, a5y = 0.f;
    float a6x = 0.f, a6y = 0.f, a7x = 0.f, a7y = 0.f;
    if (act) {   // self loop
        float2 v = __half22float2(s1h[(size_t)d * 32 + hl]);
        a0x = v.x; a0y = v.y;
    }
    int i = start;
    for (; i + 7 < end; i += 8) {
        int c0 = col[i],     c1 = col[i + 1], c2 = col[i + 2], c3 = col[i + 3];
        int c4 = col[i + 4], c5 = col[i + 5], c6 = col[i + 6], c7 = col[i + 7];
        float2 v0 = __half22float2(s1h[(size_t)c0 * 32 + hl]);
        float2 v1 = __half22float2(s1h[(size_t)c1 * 32 + hl]);
        float2 v2 = __half22float2(s1h[(size_t)c2 * 32 + hl]);
        float2 v3 = __half22float2(s1h[(size_t)c3 * 32 + hl]);
        float2 v4 = __half22float2(s1h[(size_t)c4 * 32 + hl]);
        float2 v5 = __half22float2(s1h[(size_t)c5 * 32 + hl]);
        float2 v6 = __half22float2(s1h[(size_t)c6 * 32 + hl]);
        float2 v7 = __half22float2(s1h[(size_t)c7 * 32 + hl]);
        a0x += v0.x; a0y += v0.y; a1x += v1.x; a1y += v1.y;
        a2x += v2.x; a2y += v2.y; a3x += v3.x; a3y += v3.y;
        a4x += v4.x; a4y += v4.y; a5x += v5.x; a5y += v5.y;
        a6x += v6.x; a6y += v6.y; a7x += v7.x; a7y += v7.y;
    }
    for (; i < end; ++i) {
        float2 v = __half22float2(s1h[(size_t)col[i] * 32 + hl]);
        a0x += v.x; a0y += v.y;
    }
    if (act) {
        float r = dis[d];
        float ox = r * (((a0x + a1x) + (a2x + a3x)) + ((a4x + a5x) + (a6x + a7x)));
        float oy = r * (((a0y + a1y) + (a2y + a3y)) + ((a4y + a5y) + (a6y + a7y)));
        a2h[(size_t)d * 32 + hl] = __floats2half2_rn(ox, oy);
    }
}

// ---- h1: mt = elu(elu(a2h@W2+b2)@Wm1+bm1)^T in FP16 [j][node] ----
// 64-node tiles (1563 blocks). Stage A: 4f x 4n regs, a2h fp16 + W2 global.
// Stage B: 8j x 4n regs, Wm1 global b128, tt LDS b128 (pad 68). mt writes
// coalesce: node-fastest lane mapping -> 128 B runs per j-row.
__global__ __launch_bounds__(256, 4) void h1_kernel(const __half* __restrict__ a2h,
    const float* __restrict__ W2g, const float* __restrict__ b2g,
    const float* __restrict__ Wm1g, const float* __restrict__ bm1g,
    __half* __restrict__ mt, int N) {
    __shared__ float tt[64 * TTP];     // [f][n] 17.4 KB
    __shared__ float b2s[64];
    __shared__ float bm1s[128];
    int tid = threadIdx.x;
    if (tid < 64)  b2s[tid]  = b2g[tid];
    if (tid < 128) bm1s[tid] = bm1g[tid];
    __syncthreads();

    int base = blockIdx.x * 64;
    // ---- stage A: acc[4f][4n] over k=0..63 ----
    {
        int fA = (tid >> 4) * 4;       // 16 groups of 4 features
        int nA = (tid & 15) * 4;       // 16 groups of 4 nodes
        float acc[4][4];
#pragma unroll
        for (int f = 0; f < 4; ++f) {
            float bb = b2s[fA + f];
#pragma unroll
            for (int i = 0; i < 4; ++i) acc[f][i] = bb;
        }
        const __half* r0 = a2h + (size_t)min(base + nA + 0, N - 1) * 64;
        const __half* r1 = a2h + (size_t)min(base + nA + 1, N - 1) * 64;
        const __half* r2 = a2h + (size_t)min(base + nA + 2, N - 1) * 64;
        const __half* r3 = a2h + (size_t)min(base + nA + 3, N - 1) * 64;
#pragma unroll 2
        for (int k = 0; k < 64; k += 8) {
            // 8 halves (16 B) per node row
            float4 p0 = *(const float4*)(r0 + k);
            float4 p1 = *(const float4*)(r1 + k);
            float4 p2 = *(const float4*)(r2 + k);
            float4 p3 = *(const float4*)(r3 + k);
            const __half2* q0 = (const __half2*)&p0;
            const __half2* q1 = (const __half2*)&p1;
            const __half2* q2 = (const __half2*)&p2;
            const __half2* q3 = (const __half2*)&p3;
            float av[4][8];
#pragma unroll
            for (int h = 0; h < 4; ++h) {
                float2 u0 = __half22float2(q0[h]);
                float2 u1 = __half22float2(q1[h]);
                float2 u2 = __half22float2(q2[h]);
                float2 u3 = __half22float2(q3[h]);
                av[0][2 * h] = u0.x; av[0][2 * h + 1] = u0.y;
                av[1][2 * h] = u1.x; av[1][2 * h + 1] = u1.y;
                av[2][2 * h] = u2.x; av[2][2 * h + 1] = u2.y;
                av[3][2 * h] = u3.x; av[3][2 * h + 1] = u3.y;
            }
#pragma unroll
            for (int kk = 0; kk < 8; ++kk) {
                float4 w = *(const float4*)(W2g + (k + kk) * 64 + fA);
                float wv[4] = {w.x, w.y, w.z, w.w};
#pragma unroll
                for (int f = 0; f < 4; ++f)
#pragma unroll
                    for (int i = 0; i < 4; ++i)
                        acc[f][i] = fmaf(wv[f], av[i][kk], acc[f][i]);
            }
        }
#pragma unroll
        for (int f = 0; f < 4; ++f) {
            float4 v;
            v.x = elu(acc[f][0]); v.y = elu(acc[f][1]);
            v.z = elu(acc[f][2]); v.w = elu(acc[f][3]);
            *(float4*)(tt + (fA + f) * TTP + nA) = v;
        }
    }
    __syncthreads();
    // ---- stage B: accB[8j][4n] over f=0..63 ----
    {
        int jB = (tid >> 4) * 8;       // 16 j-groups of 8
        int nB = (tid & 15) * 4;       // node-fastest: coalesced mt writes
        float accB[8][4];
#pragma unroll
        for (int j = 0; j < 8; ++j) {
            float bb = bm1s[jB + j];
#pragma unroll
            for (int i = 0; i < 4; ++i) accB[j][i] = bb;
        }
#pragma unroll 4
        for (int f = 0; f < 64; ++f) {
            float4 w0 = *(const float4*)(Wm1g + f * 128 + jB);
            float4 w1 = *(const float4*)(Wm1g + f * 128 + jB + 4);
            float4 t  = *(const float4*)(tt + f * TTP + nB);
            float wv[8] = {w0.x, w0.y, w0.z, w0.w, w1.x, w1.y, w1.z, w1.w};
            float tv[4] = {t.x, t.y, t.z, t.w};
#pragma unroll
            for (int j = 0; j < 8; ++j)
#pragma unroll
                for (int i = 0; i < 4; ++i)
                    accB[j][i] = fmaf(wv[j], tv[i], accB[j][i]);
        }
        if (base + 64 <= N) {
#pragma unroll
            for (int j = 0; j < 8; ++j) {
                __half2 h[2];
                h[0] = __floats2half2_rn(elu(accB[j][0]), elu(accB[j][1]));
                h[1] = __floats2half2_rn(elu(accB[j][2]), elu(accB[j][3]));
                *(float2*)(mt + (size_t)(jB + j) * N + base + nB) = *(float2*)h;
            }
        } else {
#pragma unroll
            for (int j = 0; j < 8; ++j)
#pragma unroll
                for (int i = 0; i < 4; ++i) {
                    int node = base + nB + i;
                    if (node < N)
                        mt[(size_t)(jB + j) * N + node] = __float2half(elu(accB[j][i]));
                }
        }
    }
}

// ---- h2: out = softmax(mt^T @ Wm2 + bm2), thread per node ----
__global__ __launch_bounds__(256) void h2_kernel(const __half* __restrict__ mt,
    const float* __restrict__ Wm2g, const float* __restrict__ bm2g,
    float* __restrict__ out, int N) {
    __shared__ float Wt[15 * 128];   // transposed [c][j]
    int tid = threadIdx.x;
    for (int i = tid; i < 15 * 128; i += 256) {
        int c = i >> 7, j = i & 127;
        Wt[i] = Wm2g[j * 15 + c];
    }
    __syncthreads();
    int node = blockIdx.x * 256 + tid;
    if (node >= N) return;
    float lg[15];
#pragma unroll
    for (int c = 0; c < 15; ++c) lg[c] = bm2g[c];
#pragma unroll 4
    for (int j4 = 0; j4 < 128; j4 += 4) {
        float m0 = __half2float(mt[(size_t)(j4 + 0) * N + node]);
        float m1 = __half2float(mt[(size_t)(j4 + 1) * N + node]);
        float m2 = __half2float(mt[(size_t)(j4 + 2) * N + node]);
        float m3 = __half2float(mt[(size_t)(j4 + 3) * N + node]);
#pragma unroll
        for (int c = 0; c < 15; ++c) {
            float4 w = *(const float4*)(Wt + c * 128 + j4);
            lg[c] = fmaf(m0, w.x, fmaf(m1, w.y, fmaf(m2, w.z, fmaf(m3, w.w, lg[c]))));
        }
    }
    float mx = lg[0];
#pragma unroll
    for (int c = 1; c < 15; ++c) mx = fmaxf(mx, lg[c]);
    float ex[15], s = 0.f;
#pragma unroll
    for (int c = 0; c < 15; ++c) { ex[c] = __expf(lg[c] - mx); s += ex[c]; }
    float inv = 1.f / s;
#pragma unroll
    for (int c = 0; c < 15; ++c) out[(size_t)node * 15 + c] = ex[c] * inv;
}

extern "C" void kernel_launch(void* const* d_in, const int* in_sizes, int n_in,
                              void* d_out, int out_size, void* d_ws, size_t ws_size,
                              hipStream_t stream) {
    const float* x   = (const float*)d_in[0];
    const int*   ei  = (const int*)d_in[1];
    const float* W1  = (const float*)d_in[2];
    const float* b1  = (const float*)d_in[3];
    const float* W2  = (const float*)d_in[4];
    const float* b2  = (const float*)d_in[5];
    const float* Wm1 = (const float*)d_in[6];
    const float* bm1 = (const float*)d_in[7];
    const float* Wm2 = (const float*)d_in[8];
    const float* bm2 = (const float*)d_in[9];
    float* out = (float*)d_out;

    int N = in_sizes[0] / 3;
    int E = in_sizes[1] / 2;
    const int* src = ei;
    const int* dst = ei + E;
    int NBK = (N + SPAN - 1) / SPAN;   // 782

    uintptr_t p = (uintptr_t)d_ws;
    auto carve = [&](size_t bytes) -> void* {
        p = (p + 255) & ~(uintptr_t)255;
        void* r = (void*)p;
        p += bytes;
        return r;
    };
    __half*   a2h     = (__half*)carve((size_t)N * 64 * 2);    // fp16 a2
    __half*   mt      = (__half*)carve((size_t)N * 128 * 2);   // [128][N] fp16; colb aliases
    int*      cursor  = (int*)carve((size_t)NBK * 4);
    int*      bbase   = (int*)carve((size_t)NBK * 4);
    int*      row_ptr = (int*)carve((size_t)(N + 1) * 4);
    float*    dis     = (float*)carve((size_t)N * 4);
    float4*   sx4     = (float4*)carve((size_t)N * 16);
    int*      col     = (int*)carve((size_t)E * 4);
    __half*   s1h     = (__half*)carve((size_t)N * 64 * 2);
    // colb (14.4 MB) aliases mt (25.6 MB): colb dead after csr_sort; mt written in h1
    unsigned* colb = (unsigned*)mt;

    hipMemsetAsync(cursor, 0, (size_t)NBK * 4, stream);

    int nChunks = (E + CH - 1) / CH;
    int waveBlocks3  = (N + 3) / 4;   // agg3: 1 node/wave, 4 waves/block
    int waveBlocks64 = (N + 7) / 8;   // agg64: 2 nodes/wave, 4 waves/block
    int nTiles = (N + 63) / 64;       // h1: 64-node tiles
    scatter_kernel<<<nChunks, 256, 0, stream>>>(src, dst, cursor, colb, E, NBK, nChunks);
    bscan_kernel<<<1, 1024, 0, stream>>>(cursor, bbase, row_ptr, NBK, N);
    csr_sort_kernel<<<NBK, 256, 0, stream>>>(colb, cursor, bbase, x, row_ptr, col, dis, sx4, N);
    agg3_kernel<<<waveBlocks3, 256, 0, stream>>>(sx4, row_ptr, col, dis, W1, b1, s1h, N);
    agg64_kernel<<<waveBlocks64, 256, 0, stream>>>((const __half2*)s1h, row_ptr, col, dis,
                                                   (__half2*)a2h, N);
    h1_kernel<<<nTiles, 256, 0, stream>>>(a2h, W2, b2, Wm1, bm1, mt, N);
    h2_kernel<<<(N + 255) / 256, 256, 0, stream>>>(mt, Wm2, bm2, out, N);
}

// Round 9
// 273.269 us; speedup vs baseline: 1.2228x; 1.2228x over previous
//
#include <hip/hip_runtime.h>
#include <hip/hip_fp16.h>
#include <math.h>

// ---------------------------------------------------------------------------
// GNN pool: 2x GCNConv(elu) + MLP(128) + Linear(15) + softmax
// N=100000, E=3200000, IN=3, HID=64, MLP_HID=128, K=15, fp32 in/out.
//
// Round-9 pipeline:
//   scatter -> bscan -> csr_sort -> agg3 (s1 fp16) -> agg64 (a2 fp16)
//   -> prep (W2,Wm1 -> fp16 transposed [n][k]) -> h1 (MFMA 16x16x32_f16:
//   a2h@W2 elu @Wm1 elu -> m fp16 [node][j]) -> h2 (m@Wm2 + softmax).
//
// r8 lesson: shrinking register blocks traded VALU efficiency for occupancy
// and lost (h1 72->86us, VALU-cycles +40%). h1 is a 2.46 GFLOP GEMM chain at
// 11% vector-fp32 efficiency -> move it to matrix cores. MFMA layouts per
// guide (m89/m91/m120-verified): A[m=lane&15][k=quad*8+j], B[k][n=lane&15]
// (k=quad*8+j), D[row=quad*4+reg][col=lane&15].
// ---------------------------------------------------------------------------

#define SPAN 128          // nodes per bucket
#define CAP  4608         // bucket capacity (mean 4092 + ~8 sigma)
#define CH   8192         // edges per scatter chunk
#define H2P  88           // h2s row pad (halfs): 12*m mod 32 -> 2-way max, 8-aligned
#define MSP2 136          // ms row pad (halfs): 8-aligned, low conflict

typedef _Float16 v8hf __attribute__((ext_vector_type(8)));
typedef float    v4f  __attribute__((ext_vector_type(4)));

__device__ __forceinline__ float elu(float v) { return v > 0.f ? v : expm1f(v); }

// ---- counting scatter: edges -> buckets by dst>>7, packed (dl<<17)|src ----
__global__ __launch_bounds__(256) void scatter_kernel(const int* __restrict__ src,
    const int* __restrict__ dst, int* __restrict__ cursor, unsigned* __restrict__ colb,
    int E, int NBK, int nChunks) {
    __shared__ int hist[1024];
    __shared__ unsigned gb[1024];
    int tid = threadIdx.x;
    for (int chunk = blockIdx.x; chunk < nChunks; chunk += gridDim.x) {
        for (int i = tid; i < NBK; i += 256) hist[i] = 0;
        __syncthreads();
        int base = chunk * CH;
        int cnt = min(CH, E - base);
        unsigned br[32], dt[32];
#pragma unroll
        for (int j = 0; j < 32; ++j) {
            int idx = j * 256 + tid;
            br[j] = 0xFFFFFFFFu;
            if (idx < cnt) {
                int e = base + idx;
                int s = src[e], d = dst[e];
                int b = d >> 7;
                int r = atomicAdd(&hist[b], 1);
                br[j] = ((unsigned)b << 13) | (unsigned)r;
                dt[j] = ((unsigned)(d & 127) << 17) | (unsigned)s;
            }
        }
        __syncthreads();
        for (int b = tid; b < NBK; b += 256) {
            int c = hist[b];
            gb[b] = (unsigned)(b * CAP) + (c ? (unsigned)atomicAdd(&cursor[b], c) : 0u);
        }
        __syncthreads();
#pragma unroll
        for (int j = 0; j < 32; ++j) {
            if (br[j] != 0xFFFFFFFFu) {
                int b = br[j] >> 13;
                int r = br[j] & 8191;
                unsigned pos = gb[b] + (unsigned)r;
                if (pos < (unsigned)(b + 1) * CAP) colb[pos] = dt[j];
            }
        }
        __syncthreads();
    }
}

// ---- exclusive scan over bucket counts -> bbase ----
__global__ __launch_bounds__(1024) void bscan_kernel(const int* __restrict__ cursor,
    int* __restrict__ bbase, int* __restrict__ row_ptr, int NBK, int N) {
    __shared__ int ls[1024];
    int t = threadIdx.x;
    int v = (t < NBK) ? min(cursor[t], CAP) : 0;
    ls[t] = v;
    __syncthreads();
    for (int off = 1; off < 1024; off <<= 1) {
        int xv = (t >= off) ? ls[t - off] : 0;
        __syncthreads();
        ls[t] += xv;
        __syncthreads();
    }
    if (t < NBK) bbase[t] = ls[t] - v;
    if (t == NBK - 1) row_ptr[N] = ls[t];
}

// ---- per-bucket counting sort: row_ptr, deg->dis, sx4, coalesced col ----
__global__ __launch_bounds__(256) void csr_sort_kernel(const unsigned* __restrict__ colb,
    const int* __restrict__ cursor, const int* __restrict__ bbase,
    const float* __restrict__ x, int* __restrict__ row_ptr, int* __restrict__ col,
    float* __restrict__ dis, float4* __restrict__ sx4, int N) {
    __shared__ unsigned ebuf[CAP];
    __shared__ int sbuf[CAP];
    __shared__ int cnt[SPAN], pref[SPAN], fill[SPAN];
    int b = blockIdx.x, tid = threadIdx.x;
    int n = min(cursor[b], CAP);
    int base = b * CAP, bb = bbase[b];
    if (tid < SPAN) cnt[tid] = 0;
    for (int i = tid; i < n; i += 256) ebuf[i] = colb[base + i];
    __syncthreads();
    for (int i = tid; i < n; i += 256) atomicAdd(&cnt[(ebuf[i] >> 17) & 127], 1);
    __syncthreads();
    if (tid < SPAN) pref[tid] = cnt[tid];
    __syncthreads();
    for (int off = 1; off < SPAN; off <<= 1) {
        int xv = (tid < SPAN && tid >= off) ? pref[tid - off] : 0;
        __syncthreads();
        if (tid < SPAN) pref[tid] += xv;
        __syncthreads();
    }
    if (tid < SPAN) {
        int ex = pref[tid] - cnt[tid];
        fill[tid] = ex;
        int node = b * SPAN + tid;
        if (node < N) {
            row_ptr[node] = bb + ex;
            float r = rsqrtf((float)(cnt[tid] + 1));
            dis[node] = r;
            float4 q;
            q.x = r * x[node * 3 + 0];
            q.y = r * x[node * 3 + 1];
            q.z = r * x[node * 3 + 2];
            q.w = 0.f;
            sx4[node] = q;
        }
    }
    __syncthreads();
    for (int i = tid; i < n; i += 256) {
        unsigned e = ebuf[i];
        int pos = atomicAdd(&fill[(e >> 17) & 127], 1);
        sbuf[pos] = (int)(e & 0x1FFFF);
    }
    __syncthreads();
    for (int i = tid; i < n; i += 256) col[bb + i] = sbuf[i];
}

// ---- layer 1: aggregate sx (float4) + W1 + bias + elu; s1h = fp16(dis*h1) ----
__global__ void agg3_kernel(const float4* __restrict__ sx4, const int* __restrict__ row_ptr,
                            const int* __restrict__ col, const float* __restrict__ dis,
                            const float* __restrict__ W1, const float* __restrict__ b1,
                            __half* __restrict__ s1h, int N) {
    int wave = (blockIdx.x * blockDim.x + threadIdx.x) >> 6;
    int lane = threadIdx.x & 63;
    if (wave >= N) return;
    int d = wave;
    int start = row_ptr[d], end = row_ptr[d + 1];
    float a0 = 0.f, a1 = 0.f, a2v = 0.f;
    for (int i = start + lane; i < end; i += 64) {
        float4 q = sx4[col[i]];
        a0 += q.x; a1 += q.y; a2v += q.z;
    }
#pragma unroll
    for (int off = 32; off; off >>= 1) {
        a0  += __shfl_xor(a0, off);
        a1  += __shfl_xor(a1, off);
        a2v += __shfl_xor(a2v, off);
    }
    float4 qd = sx4[d];   // self loop
    a0 += qd.x; a1 += qd.y; a2v += qd.z;
    float r = dis[d];
    float v = r * (a0 * W1[lane] + a1 * W1[64 + lane] + a2v * W1[128 + lane]) + b1[lane];
    s1h[(size_t)d * 64 + lane] = __float2half(r * elu(v));
}

// ---- layer 2: 2 nodes/wave, half2 gathers; writes a2h FP16 ----
__global__ void agg64_kernel(const __half2* __restrict__ s1h, const int* __restrict__ row_ptr,
                             const int* __restrict__ col, const float* __restrict__ dis,
                             __half2* __restrict__ a2h, int N) {
    int wave = (blockIdx.x * blockDim.x + threadIdx.x) >> 6;
    int lane = threadIdx.x & 63;
    int hl = lane & 31;
    int d = wave * 2 + (lane >> 5);
    bool act = d < N;
    int start = 0, end = 0;
    if (act) { start = row_ptr[d]; end = row_ptr[d + 1]; }
    float a0x = 0.f, a0y = 0.f, a1x = 0.f, a1y = 0.f;
    float a2x = 0.f, a2y = 0.f, a3x = 0.f, a3y = 0.f;
    float a4x = 0.f, a4y = 0.f, a5x = 0.f, a5y = 0.f;
    float a6x = 0.f, a6y = 0.f, a7x = 0.f, a7y = 0.f;
    if (act) {   // self loop
        float2 v = __half22float2(s1h[(size_t)d * 32 + hl]);
        a0x = v.x; a0y = v.y;
    }
    int i = start;
    for (; i + 7 < end; i += 8) {
        int c0 = col[i],     c1 = col[i + 1], c2 = col[i + 2], c3 = col[i + 3];
        int c4 = col[i + 4], c5 = col[i + 5], c6 = col[i + 6], c7 = col[i + 7];
        float2 v0 = __half22float2(s1h[(size_t)c0 * 32 + hl]);
        float2 v1 = __half22float2(s1h[(size_t)c1 * 32 + hl]);
        float2 v2 = __half22float2(s1h[(size_t)c2 * 32 + hl]);
        float2 v3 = __half22float2(s1h[(size_t)c3 * 32 + hl]);
        float2 v4 = __half22float2(s1h[(size_t)c4 * 32 + hl]);
        float2 v5 = __half22float2(s1h[(size_t)c5 * 32 + hl]);
        float2 v6 = __half22float2(s1h[(size_t)c6 * 32 + hl]);
        float2 v7 = __half22float2(s1h[(size_t)c7 * 32 + hl]);
        a0x += v0.x; a0y += v0.y; a1x += v1.x; a1y += v1.y;
        a2x += v2.x; a2y += v2.y; a3x += v3.x; a3y += v3.y;
        a4x += v4.x; a4y += v4.y; a5x += v5.x; a5y += v5.y;
        a6x += v6.x; a6y += v6.y; a7x += v7.x; a7y += v7.y;
    }
    for (; i < end; ++i) {
        float2 v = __half22float2(s1h[(size_t)col[i] * 32 + hl]);
        a0x += v.x; a0y += v.y;
    }
    if (act) {
        float r = dis[d];
        float ox = r * (((a0x + a1x) + (a2x + a3x)) + ((a4x + a5x) + (a6x + a7x)));
        float oy = r * (((a0y + a1y) + (a2y + a3y)) + ((a4y + a5y) + (a6y + a7y)));
        a2h[(size_t)d * 32 + hl] = __floats2half2_rn(ox, oy);
    }
}

// ---- prep: W2t[f][k] = fp16(W2[k][f]); Wm1t[j][f] = fp16(Wm1[f][j]) ----
__global__ __launch_bounds__(256) void prep_kernel(const float* __restrict__ W2,
    const float* __restrict__ Wm1, __half* __restrict__ W2t, __half* __restrict__ Wm1t) {
    int tid = blockIdx.x * 256 + threadIdx.x;
    if (tid < 64 * 64) {
        int f = tid >> 6, k = tid & 63;
        W2t[f * 64 + k] = __float2half(W2[k * 64 + f]);
    }
    if (tid < 128 * 64) {
        int j = tid >> 6, f = tid & 63;
        Wm1t[j * 64 + f] = __float2half(Wm1[f * 128 + j]);
    }
}

// ---- h1 (MFMA): m = elu(elu(a2h@W2+b2)@Wm1+bm1), fp16 [node][j] ----
// Block = 64 nodes (4 waves x 16). Stage A: 8 mfma/wave; LDS h2s for
// C->A layout change; Stage B: 16 mfma/wave; LDS ms -> coalesced fp16 out.
__global__ __launch_bounds__(256) void h1_kernel(const __half* __restrict__ a2h,
    const __half* __restrict__ W2t, const float* __restrict__ b2g,
    const __half* __restrict__ Wm1t, const float* __restrict__ bm1g,
    __half* __restrict__ m, int N) {
    __shared__ __align__(16) __half h2s[64 * H2P];   // 11.3 KB
    __shared__ __align__(16) __half ms[64 * MSP2];   // 17.4 KB
    __shared__ float b2s[64], bm1s[128];
    int tid = threadIdx.x;
    if (tid < 64)  b2s[tid]  = b2g[tid];
    if (tid < 128) bm1s[tid] = bm1g[tid];
    __syncthreads();

    int wave = tid >> 6, lane = tid & 63;
    int q = lane >> 4, l16 = lane & 15;
    int base = blockIdx.x * 64;

    // ---- stage A: D[m=node16][n=f] = a2h @ W2 ----
    {
        int nodeRow = base + wave * 16 + l16;             // A-frag m index
        size_t arow = (size_t)min(nodeRow, N - 1) * 64;
        v8hf af0 = *(const v8hf*)(a2h + arow + q * 8);        // k = 0..31
        v8hf af1 = *(const v8hf*)(a2h + arow + 32 + q * 8);   // k = 32..63
#pragma unroll
        for (int fb = 0; fb < 4; ++fb) {
            float bb = b2s[fb * 16 + l16];                // bias depends on n only
            v4f acc = {bb, bb, bb, bb};
            v8hf b0 = *(const v8hf*)(W2t + (fb * 16 + l16) * 64 + q * 8);
            v8hf b1 = *(const v8hf*)(W2t + (fb * 16 + l16) * 64 + 32 + q * 8);
            acc = __builtin_amdgcn_mfma_f32_16x16x32_f16(af0, b0, acc, 0, 0, 0);
            acc = __builtin_amdgcn_mfma_f32_16x16x32_f16(af1, b1, acc, 0, 0, 0);
            // D: row(node16) = q*4+r, col(f) = fb*16+l16
#pragma unroll
            for (int r = 0; r < 4; ++r)
                h2s[(wave * 16 + q * 4 + r) * H2P + fb * 16 + l16] =
                    __float2half(elu(acc[r]));
        }
    }
    __syncthreads();
    // ---- stage B: D[m=node16][n=j] = h2 @ Wm1 ----
    {
        int arow = (wave * 16 + l16) * H2P;               // A-frag m = l16
        v8hf af0 = *(const v8hf*)(h2s + arow + q * 8);        // k(f) = 0..31
        v8hf af1 = *(const v8hf*)(h2s + arow + 32 + q * 8);   // k(f) = 32..63
#pragma unroll
        for (int jb = 0; jb < 8; ++jb) {
            float bb = bm1s[jb * 16 + l16];
            v4f acc = {bb, bb, bb, bb};
            v8hf b0 = *(const v8hf*)(Wm1t + (jb * 16 + l16) * 64 + q * 8);
            v8hf b1 = *(const v8hf*)(Wm1t + (jb * 16 + l16) * 64 + 32 + q * 8);
            acc = __builtin_amdgcn_mfma_f32_16x16x32_f16(af0, b0, acc, 0, 0, 0);
            acc = __builtin_amdgcn_mfma_f32_16x16x32_f16(af1, b1, acc, 0, 0, 0);
#pragma unroll
            for (int r = 0; r < 4; ++r)
                ms[(wave * 16 + q * 4 + r) * MSP2 + jb * 16 + l16] =
                    __float2half(elu(acc[r]));
        }
    }
    __syncthreads();
    // ---- coalesced copy ms -> m[node][128] fp16 ----
    for (int i = tid; i < 64 * 16; i += 256) {   // 64 rows x 16 chunks of 8 halfs
        int row = i >> 4, c8 = i & 15;
        int node = base + row;
        if (node < N)
            *(float4*)(m + (size_t)node * 128 + c8 * 8) =
                *(const float4*)(ms + row * MSP2 + c8 * 8);
    }
}

// ---- h2: out = softmax(m@Wm2 + bm2), thread per node, fp16 row reads ----
__global__ __launch_bounds__(256) void h2_kernel(const __half* __restrict__ m,
    const float* __restrict__ Wm2g, const float* __restrict__ bm2g,
    float* __restrict__ out, int N) {
    __shared__ float Wt[15 * 128];   // transposed [c][j]
    int tid = threadIdx.x;
    for (int i = tid; i < 15 * 128; i += 256) {
        int c = i >> 7, j = i & 127;
        Wt[i] = Wm2g[j * 15 + c];
    }
    __syncthreads();
    int node = blockIdx.x * 256 + tid;
    if (node >= N) return;
    float lg[15];
#pragma unroll
    for (int c = 0; c < 15; ++c) lg[c] = bm2g[c];
    const __half* row = m + (size_t)node * 128;
#pragma unroll 2
    for (int j8 = 0; j8 < 128; j8 += 8) {
        float4 raw = *(const float4*)(row + j8);
        const __half2* hp = (const __half2*)&raw;
        float mv[8];
#pragma unroll
        for (int h = 0; h < 4; ++h) {
            float2 u = __half22float2(hp[h]);
            mv[2 * h] = u.x; mv[2 * h + 1] = u.y;
        }
#pragma unroll
        for (int c = 0; c < 15; ++c) {
            float4 w0 = *(const float4*)(Wt + c * 128 + j8);
            float4 w1 = *(const float4*)(Wt + c * 128 + j8 + 4);
            lg[c] = fmaf(mv[0], w0.x, fmaf(mv[1], w0.y, fmaf(mv[2], w0.z,
                    fmaf(mv[3], w0.w, fmaf(mv[4], w1.x, fmaf(mv[5], w1.y,
                    fmaf(mv[6], w1.z, fmaf(mv[7], w1.w, lg[c]))))))));
        }
    }
    float mx = lg[0];
#pragma unroll
    for (int c = 1; c < 15; ++c) mx = fmaxf(mx, lg[c]);
    float ex[15], s = 0.f;
#pragma unroll
    for (int c = 0; c < 15; ++c) { ex[c] = __expf(lg[c] - mx); s += ex[c]; }
    float inv = 1.f / s;
#pragma unroll
    for (int c = 0; c < 15; ++c) out[(size_t)node * 15 + c] = ex[c] * inv;
}

extern "C" void kernel_launch(void* const* d_in, const int* in_sizes, int n_in,
                              void* d_out, int out_size, void* d_ws, size_t ws_size,
                              hipStream_t stream) {
    const float* x   = (const float*)d_in[0];
    const int*   ei  = (const int*)d_in[1];
    const float* W1  = (const float*)d_in[2];
    const float* b1  = (const float*)d_in[3];
    const float* W2  = (const float*)d_in[4];
    const float* b2  = (const float*)d_in[5];
    const float* Wm1 = (const float*)d_in[6];
    const float* bm1 = (const float*)d_in[7];
    const float* Wm2 = (const float*)d_in[8];
    const float* bm2 = (const float*)d_in[9];
    float* out = (float*)d_out;

    int N = in_sizes[0] / 3;
    int E = in_sizes[1] / 2;
    const int* src = ei;
    const int* dst = ei + E;
    int NBK = (N + SPAN - 1) / SPAN;   // 782

    uintptr_t p = (uintptr_t)d_ws;
    auto carve = [&](size_t bytes) -> void* {
        p = (p + 255) & ~(uintptr_t)255;
        void* r = (void*)p;
        p += bytes;
        return r;
    };
    __half*   a2h     = (__half*)carve((size_t)N * 64 * 2);    // fp16 a2
    __half*   m       = (__half*)carve((size_t)N * 128 * 2);   // fp16 [node][j]; colb aliases
    int*      cursor  = (int*)carve((size_t)NBK * 4);
    int*      bbase   = (int*)carve((size_t)NBK * 4);
    int*      row_ptr = (int*)carve((size_t)(N + 1) * 4);
    float*    dis     = (float*)carve((size_t)N * 4);
    float4*   sx4     = (float4*)carve((size_t)N * 16);
    int*      col     = (int*)carve((size_t)E * 4);
    __half*   s1h     = (__half*)carve((size_t)N * 64 * 2);
    __half*   W2t     = (__half*)carve(64 * 64 * 2);
    __half*   Wm1t    = (__half*)carve(128 * 64 * 2);
    // colb (14.4 MB) aliases m (25.6 MB): colb dead after csr_sort; m written in h1
    unsigned* colb = (unsigned*)m;

    hipMemsetAsync(cursor, 0, (size_t)NBK * 4, stream);

    int nChunks = (E + CH - 1) / CH;
    int waveBlocks3  = (N + 3) / 4;   // agg3: 1 node/wave, 4 waves/block
    int waveBlocks64 = (N + 7) / 8;   // agg64: 2 nodes/wave, 4 waves/block
    int nTiles = (N + 63) / 64;       // h1: 64-node tiles
    scatter_kernel<<<nChunks, 256, 0, stream>>>(src, dst, cursor, colb, E, NBK, nChunks);
    bscan_kernel<<<1, 1024, 0, stream>>>(cursor, bbase, row_ptr, NBK, N);
    prep_kernel<<<32, 256, 0, stream>>>(W2, Wm1, W2t, Wm1t);
    csr_sort_kernel<<<NBK, 256, 0, stream>>>(colb, cursor, bbase, x, row_ptr, col, dis, sx4, N);
    agg3_kernel<<<waveBlocks3, 256, 0, stream>>>(sx4, row_ptr, col, dis, W1, b1, s1h, N);
    agg64_kernel<<<waveBlocks64, 256, 0, stream>>>((const __half2*)s1h, row_ptr, col, dis,
                                                   (__half2*)a2h, N);
    h1_kernel<<<nTiles, 256, 0, stream>>>(a2h, W2t, b2, Wm1t, bm1, m, N);
    h2_kernel<<<(N + 255) / 256, 256, 0, stream>>>(m, Wm2, bm2, out, N);
}